// Round 8
// baseline (137.217 us; speedup 1.0000x reference)
//
#include <hip/hip_runtime.h>

#define N_PAIR 3840

typedef short bf16x8 __attribute__((ext_vector_type(8)));
typedef float f32x4 __attribute__((ext_vector_type(4)));

static __device__ __forceinline__ ushort f2bf(float f) {
    uint x = __float_as_uint(f);
    uint r = (x + 0x7FFFu + ((x >> 16) & 1u)) >> 16;
    return (ushort)r;
}
static __device__ __forceinline__ float bf2f(ushort u) {
    return __uint_as_float(((uint)u) << 16);
}

// async global->LDS, 16B per lane; LDS dest is lane-linear (base + lane*16)
#define GLOAD16(GP, LP)                                                        \
    __builtin_amdgcn_global_load_lds(                                          \
        (const __attribute__((address_space(1))) void*)(GP),                   \
        (__attribute__((address_space(3))) void*)(LP), 16, 0, 0)

// ---------------- transpose + convert: in (K,N) f32 -> out (N,Kpad) bf16, zero-padded
__global__ void transpose_convert(const float* __restrict__ in0,
                                  const float* __restrict__ in1,
                                  const float* __restrict__ in2,
                                  ushort* __restrict__ out,
                                  int K, int N, int Kpad) {
    const float* in = (blockIdx.z == 0) ? in0 : (blockIdx.z == 1 ? in1 : in2);
    ushort* o = out + (size_t)blockIdx.z * N * Kpad;
    __shared__ float tile[64][65];
    int k0 = blockIdx.x * 64, n0 = blockIdx.y * 64;
    int t = threadIdx.x;
    int r = t >> 2, c4 = (t & 3) * 16;
#pragma unroll
    for (int i = 0; i < 16; i++) {
        int k = k0 + r, n = n0 + c4 + i;
        tile[r][c4 + i] = (k < K && n < N) ? in[(size_t)k * N + n] : 0.f;
    }
    __syncthreads();
#pragma unroll
    for (int i = 0; i < 16; i++) {
        int n = n0 + r, k = k0 + c4 + i;
        if (n < N && k < Kpad) o[(size_t)n * Kpad + k] = f2bf(tile[c4 + i][r]);
    }
}

// W2 (z=0..2) + Wc1 (z=3) in one launch
__global__ void transpose_convert2(const float* __restrict__ Ws2,
                                   const float* __restrict__ Wo2,
                                   const float* __restrict__ Wu2,
                                   const float* __restrict__ Wc1,
                                   ushort* __restrict__ W2T,
                                   ushort* __restrict__ WC1T) {
    int z = blockIdx.z;
    const float* in; ushort* o; int K, N, Kpad;
    if (z < 3) {
        in = (z == 0) ? Ws2 : (z == 1 ? Wo2 : Wu2);
        o = W2T + (size_t)z * 256 * 512; K = 512; N = 256; Kpad = 512;
    } else {
        in = Wc1; o = WC1T; K = 275; N = 256; Kpad = 288;
    }
    __shared__ float tile[64][65];
    int k0 = blockIdx.x * 64, n0 = blockIdx.y * 64;
    int t = threadIdx.x;
    int r = t >> 2, c4 = (t & 3) * 16;
#pragma unroll
    for (int i = 0; i < 16; i++) {
        int k = k0 + r, n = n0 + c4 + i;
        tile[r][c4 + i] = (k < K && n < N) ? in[(size_t)k * N + n] : 0.f;
    }
    __syncthreads();
#pragma unroll
    for (int i = 0; i < 16; i++) {
        int n = n0 + r, k = k0 + c4 + i;
        if (n < N && k < Kpad) o[(size_t)n * Kpad + k] = f2bf(tile[c4 + i][r]);
    }
}

// ---------------- LDS helpers: 128B rows (BK=64), XOR swizzle
__device__ __forceinline__ bf16x8 frag_ld(const ushort* __restrict__ lds, int row, int colbyte) {
    int off = (row << 7) + (colbyte ^ ((row & 7) << 4));
    return *reinterpret_cast<const bf16x8*>(reinterpret_cast<const char*>(lds) + off);
}
// 64B rows (BK=32)
__device__ __forceinline__ bf16x8 frag32_ld(const ushort* __restrict__ lds, int row, int colbyte) {
    int off = (row << 6) + (colbyte ^ ((row & 3) << 4));
    return *reinterpret_cast<const bf16x8*>(reinterpret_cast<const char*>(lds) + off);
}

// ---------------- GEMM1 main: partial x @ W1t over half of K -> f32 partials
// BM=128 BN=128 BK=64 (m93/m97 density: 16 MFMA/wave/k-slice), 4 waves (2x2),
// split-K=2, single 32KB LDS buffer, 2 barriers/K-step, TLP via 720 blocks.
__global__ __launch_bounds__(256) void gemm1_main(const float* __restrict__ xs,
                                                  const float* __restrict__ xo,
                                                  const float* __restrict__ xu,
                                                  const ushort* __restrict__ w1t,
                                                  float* __restrict__ part) {
    // 720 blocks = 8 XCDs x 90; within chunk: (nt,ks) fastest -> 8 consecutive
    // ids share one A 128-row strip (L2-local)
    int bid = blockIdx.x;
    int w = (bid & 7) * 90 + (bid >> 3);
    int br = w / 240; int r = w - br * 240;
    int mt = r >> 3, nt = (r >> 1) & 3, ks = r & 1;

    const float* x = br == 0 ? xs : (br == 1 ? xo : xu);
    const ushort* wt = w1t + (size_t)br * 512 * 2048;
    float* out = part + ((size_t)(ks * 3 + br)) * 3840 * 512;

    __shared__ ushort As[128 * 64];
    __shared__ ushort Bs[128 * 64];
    int t = threadIdx.x, lane = t & 63, wid = t >> 6;
    int wr = wid >> 1, wc = wid & 1;
    int m0 = mt * 128, n0 = nt * 128, k0 = ks * 1024;
    const float* asrc = x + (size_t)m0 * 2048 + k0;
    const ushort* bsrc = wt + (size_t)n0 * 2048 + k0;

    int ar = t >> 1, ac = (t & 1) * 32;  // A: 2 threads/row, 32 f32 each

    f32x4 acc[4][4] = {};
    for (int kt = 0; kt < 1024; kt += 64) {
        __syncthreads();  // previous tile's readers done
        // B: 128x64 bf16 via gload_lds w16, pre-swizzled source (4 granules/thread)
#pragma unroll
        for (int it = 0; it < 4; it++) {
            int g = (wid * 4 + it) * 64 + lane;
            int rr = g >> 3, cc = g & 7;
            const ushort* gp = bsrc + (size_t)rr * 2048 + kt + ((cc ^ (rr & 7)) << 3);
            GLOAD16(gp, &Bs[g * 8]);
        }
        // A: 128x64 f32 -> bf16, reg-staged
        {
            const float4* g = reinterpret_cast<const float4*>(asrc + (size_t)ar * 2048 + kt + ac);
            float4 v0 = g[0], v1 = g[1], v2 = g[2], v3 = g[3];
            float4 v4 = g[4], v5 = g[5], v6 = g[6], v7 = g[7];
            char* ab = reinterpret_cast<char*>(&As[0]);
            union { bf16x8 v; ushort us[8]; } pk;
#pragma unroll
            for (int i = 0; i < 4; i++) { pk.us[i] = f2bf(v0[i]); pk.us[4 + i] = f2bf(v1[i]); }
            *reinterpret_cast<bf16x8*>(ab + ((ar << 7) + (((ac + 0) << 1) ^ ((ar & 7) << 4)))) = pk.v;
#pragma unroll
            for (int i = 0; i < 4; i++) { pk.us[i] = f2bf(v2[i]); pk.us[4 + i] = f2bf(v3[i]); }
            *reinterpret_cast<bf16x8*>(ab + ((ar << 7) + (((ac + 8) << 1) ^ ((ar & 7) << 4)))) = pk.v;
#pragma unroll
            for (int i = 0; i < 4; i++) { pk.us[i] = f2bf(v4[i]); pk.us[4 + i] = f2bf(v5[i]); }
            *reinterpret_cast<bf16x8*>(ab + ((ar << 7) + (((ac + 16) << 1) ^ ((ar & 7) << 4)))) = pk.v;
#pragma unroll
            for (int i = 0; i < 4; i++) { pk.us[i] = f2bf(v6[i]); pk.us[4 + i] = f2bf(v7[i]); }
            *reinterpret_cast<bf16x8*>(ab + ((ar << 7) + (((ac + 24) << 1) ^ ((ar & 7) << 4)))) = pk.v;
        }
        __syncthreads();  // drains gloads + ds writes
#pragma unroll
        for (int kk = 0; kk < 64; kk += 32) {
            int cb = (kk + ((lane >> 4) << 3)) << 1;
            bf16x8 a[4], b[4];
#pragma unroll
            for (int i = 0; i < 4; i++) a[i] = frag_ld(&As[0], wr * 64 + i * 16 + (lane & 15), cb);
#pragma unroll
            for (int f = 0; f < 4; f++) b[f] = frag_ld(&Bs[0], wc * 64 + f * 16 + (lane & 15), cb);
#pragma unroll
            for (int i = 0; i < 4; i++)
#pragma unroll
                for (int j = 0; j < 4; j++)
                    acc[i][j] = __builtin_amdgcn_mfma_f32_16x16x32_bf16(a[i], b[j], acc[i][j], 0, 0, 0);
        }
    }
    // store f32 partials (no bias; reduce kernel applies bias+relu+cvt)
    int rb = m0 + wr * 64 + ((lane >> 4) << 2);
    int cb0 = n0 + wc * 64 + (lane & 15);
#pragma unroll
    for (int j = 0; j < 4; j++) {
        int col = cb0 + j * 16;
#pragma unroll
        for (int i = 0; i < 4; i++)
#pragma unroll
            for (int q = 0; q < 4; q++)
                out[(size_t)(rb + i * 16 + q) * 512 + col] = acc[i][j][q];
    }
}

// ---------------- reduce: H1 = relu(part0 + part1 + b1) -> bf16
__global__ void reduce_h1(const float* __restrict__ part,
                          const float* __restrict__ bs1,
                          const float* __restrict__ bo1,
                          const float* __restrict__ bu1,
                          ushort* __restrict__ h1) {
    const size_t D = (size_t)3840 * 512;
    size_t e = ((size_t)blockIdx.x * 256 + threadIdx.x) * 8;
    if (e >= 3 * D) return;
    int br = (int)(e / D);
    int col = (int)(e & 511);
    const float* bias = br == 0 ? bs1 : (br == 1 ? bo1 : bu1);
    const float4* p0 = reinterpret_cast<const float4*>(part + e);
    const float4* p1 = reinterpret_cast<const float4*>(part + 3 * D + e);
    const float4* bp = reinterpret_cast<const float4*>(bias + col);
    float4 a0 = p0[0], a1 = p0[1];
    float4 b0 = p1[0], b1 = p1[1];
    float4 c0 = bp[0], c1 = bp[1];
    union { bf16x8 v; ushort us[8]; } r;
#pragma unroll
    for (int i = 0; i < 4; i++) {
        float v = a0[i] + b0[i] + c0[i];
        r.us[i] = f2bf(v > 0.f ? v : 0.f);
        float w = a1[i] + b1[i] + c1[i];
        r.us[4 + i] = f2bf(w > 0.f ? w : 0.f);
    }
    *reinterpret_cast<bf16x8*>(h1 + e) = r.v;
}

// ---------------- GEMM2: h2br = relu(h1 @ W2t + b2) -> bf16 3x3840x256
// BM=64 BN=128 BK=64; BOTH operands via global_load_lds w16, pre-swizzled source.
__global__ __launch_bounds__(256) void gemm2(const ushort* __restrict__ h1,
                                             const ushort* __restrict__ w2t,
                                             const float* __restrict__ b_s,
                                             const float* __restrict__ b_o,
                                             const float* __restrict__ b_u,
                                             ushort* __restrict__ h2br) {
    // 360 blocks = 8 x 45, y fastest
    int bid = blockIdx.x;
    int w = (bid & 7) * 45 + (bid >> 3);
    int br = w / 120; int r = w - br * 120;
    int xt = r >> 1, yt = r & 1;

    const ushort* A = h1 + (size_t)br * 3840 * 512;
    const ushort* B = w2t + (size_t)br * 256 * 512;
    const float* bias = br == 0 ? b_s : (br == 1 ? b_o : b_u);
    ushort* out = h2br + (size_t)br * 3840 * 256;

    __shared__ ushort As[2][64 * 64];
    __shared__ ushort Bs[2][128 * 64];
    int t = threadIdx.x, lane = t & 63, wid = t >> 6;
    int wr = wid >> 1, wc = wid & 1;
    int m0 = xt * 64, n0 = yt * 128;
    const ushort* asrc = A + (size_t)m0 * 512;
    const ushort* bsrc = B + (size_t)n0 * 512;

#define G2_GLOADS(BUF, KT)                                                                \
    {                                                                                     \
        _Pragma("unroll")                                                                 \
        for (int it = 0; it < 2; it++) {                                                  \
            int g = (wid * 2 + it) * 64 + lane;                                           \
            int rr = g >> 3, cc = g & 7;                                                  \
            const ushort* gp = asrc + (size_t)rr * 512 + (KT) + ((cc ^ (rr & 7)) << 3);   \
            GLOAD16(gp, &As[BUF][g * 8]);                                                 \
        }                                                                                 \
        _Pragma("unroll")                                                                 \
        for (int it = 0; it < 4; it++) {                                                  \
            int g = (wid * 4 + it) * 64 + lane;                                           \
            int rr = g >> 3, cc = g & 7;                                                  \
            const ushort* gp = bsrc + (size_t)rr * 512 + (KT) + ((cc ^ (rr & 7)) << 3);   \
            GLOAD16(gp, &Bs[BUF][g * 8]);                                                 \
        }                                                                                 \
    }
#define G2_MFMA(BUF)                                                                      \
    _Pragma("unroll")                                                                     \
    for (int kk = 0; kk < 64; kk += 32) {                                                 \
        int cb = (kk + ((lane >> 4) << 3)) << 1;                                          \
        bf16x8 a[2], b[4];                                                                \
        _Pragma("unroll")                                                                 \
        for (int i = 0; i < 2; i++) a[i] = frag_ld(&As[BUF][0], wr * 32 + i * 16 + (lane & 15), cb); \
        _Pragma("unroll")                                                                 \
        for (int f = 0; f < 4; f++) b[f] = frag_ld(&Bs[BUF][0], wc * 64 + f * 16 + (lane & 15), cb); \
        _Pragma("unroll")                                                                 \
        for (int i = 0; i < 2; i++)                                                       \
            _Pragma("unroll")                                                             \
            for (int j = 0; j < 4; j++)                                                   \
                acc[i][j] = __builtin_amdgcn_mfma_f32_16x16x32_bf16(a[i], b[j], acc[i][j], 0, 0, 0); \
    }

    f32x4 acc[2][4] = {};
    G2_GLOADS(0, 0)
    __syncthreads();
    int cur = 0;
    for (int kt = 0; kt < 512; kt += 64) {
        if (kt + 64 < 512) G2_GLOADS(cur ^ 1, kt + 64)
        G2_MFMA(cur)
        __syncthreads();
        cur ^= 1;
    }
    int rb = m0 + wr * 32 + ((lane >> 4) << 2);
    int cb0 = n0 + wc * 64 + (lane & 15);
#pragma unroll
    for (int j = 0; j < 4; j++) {
        int col = cb0 + j * 16;
        float bv = bias[col];
#pragma unroll
        for (int i = 0; i < 2; i++)
#pragma unroll
            for (int q = 0; q < 4; q++) {
                int row = rb + i * 16 + q;
                float v = acc[i][j][q] + bv;
                v = v > 0.f ? v : 0.f;
                out[(size_t)row * 256 + col] = f2bf(v);
            }
    }
#undef G2_GLOADS
#undef G2_MFMA
}

// ---------------- appear = u - o - s -> hin[:,0:256); loc features -> hin[:,256:288)
__global__ void appear_pack(const ushort* __restrict__ h2br,
                            ushort* __restrict__ hin,
                            const float* __restrict__ boxes,
                            const float* __restrict__ im_info,
                            const int* __restrict__ o1, const int* __restrict__ o2,
                            const int* __restrict__ u, const int* __restrict__ im) {
    int i = blockIdx.x * 256 + threadIdx.x;
    if (i < N_PAIR * 32) {
        int p = i >> 5, ch = (i & 31) * 8;
        const ushort* ps = h2br + (size_t)p * 256 + ch;
        bf16x8 vs = *reinterpret_cast<const bf16x8*>(ps);
        bf16x8 vo = *reinterpret_cast<const bf16x8*>(ps + (size_t)3840 * 256);
        bf16x8 vu = *reinterpret_cast<const bf16x8*>(ps + (size_t)2 * 3840 * 256);
        union { bf16x8 v; ushort us[8]; } r;
#pragma unroll
        for (int j = 0; j < 8; j++)
            r.us[j] = f2bf(bf2f(((ushort)vu[j])) - bf2f(((ushort)vo[j])) - bf2f(((ushort)vs[j])));
        *reinterpret_cast<bf16x8*>(hin + (size_t)p * 288 + ch) = r.v;
    }
    if (blockIdx.x < 15) {
        int p = blockIdx.x * 256 + threadIdx.x;
        const float* sb = boxes + 5 * o1[p] + 1;
        const float* ob = boxes + 5 * o2[p] + 1;
        const float* ub = boxes + 5 * u[p] + 1;
        const float* ii = im_info + 3 * im[p];
        float hi = ii[0], wi = ii[1];
        float x_s = (sb[0] + sb[2]) * 0.5f, y_s = (sb[1] + sb[3]) * 0.5f;
        float w_s = sb[2] - sb[0], h_s = sb[3] - sb[1];
        float x_o = (ob[0] + ob[2]) * 0.5f, y_o = (ob[1] + ob[3]) * 0.5f;
        float w_o = ob[2] - ob[0], h_o = ob[3] - ob[1];
        float a_s = w_s * h_s, a_o = w_o * h_o;
        float a_u = (ub[2] - ub[0]) * (ub[3] - ub[1]);
        float area = wi * hi;
        float f[19];
        f[0] = x_s / wi;            f[1] = y_s / hi;
        f[2] = (x_s + w_s) / wi;    f[3] = (y_s + h_s) / hi;
        f[4] = a_s / area;
        f[5] = x_o / wi;            f[6] = y_o / hi;
        f[7] = (x_o + w_o) / wi;    f[8] = (y_o + h_o) / hi;
        f[9] = a_o / area;
        f[10] = (x_s - x_o) / w_o;  f[11] = (y_s - y_o) / h_o;
        f[12] = logf(w_s / w_o);    f[13] = logf(h_s / h_o);
        f[14] = (x_o - x_s) / w_s;  f[15] = (y_o - y_s) / h_s;
        f[16] = logf(w_o / w_s);    f[17] = logf(h_o / h_s);
        f[18] = a_u / area;
        ushort* row = hin + (size_t)p * 288 + 256;
#pragma unroll
        for (int k = 0; k < 19; k++) row[k] = f2bf(f[k]);
#pragma unroll
        for (int k = 19; k < 32; k++) row[k] = 0;
    }
}

// ---------------- GEMM3: h2 = relu(hin (3840x288) @ Wc1t + bc1) -> bf16 3840x256
__global__ __launch_bounds__(256) void gemm3(const ushort* __restrict__ hin,
                                             const ushort* __restrict__ wc1t,
                                             const float* __restrict__ bc1,
                                             ushort* __restrict__ h2) {
    __shared__ ushort As[2][64 * 32];
    __shared__ ushort Bs[2][128 * 32];
    int t = threadIdx.x, lane = t & 63, wid = t >> 6;
    int wr = wid >> 1, wc = wid & 1;
    int m0 = blockIdx.x * 64, n0 = blockIdx.y * 128;
    const ushort* asrc = hin + (size_t)m0 * 288;
    const ushort* bsrc = wc1t + (size_t)n0 * 288;

    int ar = t >> 2, ac = (t & 3) * 8;
    bf16x8 pa, pb[2];
    auto issue = [&](int kt) {
        pa = *reinterpret_cast<const bf16x8*>(asrc + (size_t)ar * 288 + kt + ac);
#pragma unroll
        for (int it = 0; it < 2; it++) {
            int e = (it * 256 + t) * 8;
            int rr = e >> 5, cc = e & 31;
            pb[it] = *reinterpret_cast<const bf16x8*>(bsrc + (size_t)rr * 288 + kt + cc);
        }
    };
    auto commit = [&](int buf) {
        char* ab = reinterpret_cast<char*>(&As[buf][0]);
        int off0 = (ar << 6) + ((ac << 1) ^ ((ar & 3) << 4));
        *reinterpret_cast<bf16x8*>(ab + off0) = pa;
        char* bb = reinterpret_cast<char*>(&Bs[buf][0]);
#pragma unroll
        for (int it = 0; it < 2; it++) {
            int e = (it * 256 + t) * 8;
            int rr = e >> 5, cc = e & 31;
            int off = (rr << 6) + ((cc << 1) ^ ((rr & 3) << 4));
            *reinterpret_cast<bf16x8*>(bb + off) = pb[it];
        }
    };

    f32x4 acc[2][4] = {};
    issue(0);
    commit(0);
    __syncthreads();
    int cur = 0;
    for (int kt = 0; kt < 288; kt += 32) {
        int nxt = kt + 32;
        if (nxt < 288) issue(nxt);
        int cb = ((lane >> 4) << 3) << 1;
        bf16x8 a[2], b[4];
#pragma unroll
        for (int i = 0; i < 2; i++) a[i] = frag32_ld(&As[cur][0], wr * 32 + i * 16 + (lane & 15), cb);
#pragma unroll
        for (int f = 0; f < 4; f++) b[f] = frag32_ld(&Bs[cur][0], wc * 64 + f * 16 + (lane & 15), cb);
#pragma unroll
        for (int i = 0; i < 2; i++)
#pragma unroll
            for (int j = 0; j < 4; j++)
                acc[i][j] = __builtin_amdgcn_mfma_f32_16x16x32_bf16(a[i], b[j], acc[i][j], 0, 0, 0);
        if (nxt < 288) commit(cur ^ 1);
        __syncthreads();
        cur ^= 1;
    }
    int rb = m0 + wr * 32 + ((lane >> 4) << 2);
    int cb0 = n0 + wc * 64 + (lane & 15);
#pragma unroll
    for (int j = 0; j < 4; j++) {
        int col = cb0 + j * 16;
        float bv = bc1[col];
#pragma unroll
        for (int i = 0; i < 2; i++)
#pragma unroll
            for (int q = 0; q < 4; q++) {
                int row = rb + i * 16 + q;
                float v = acc[i][j][q] + bv;
                v = v > 0.f ? v : 0.f;
                h2[(size_t)row * 256 + col] = f2bf(v);
            }
    }
}

// ---------------- final: out = h2 (3840x256 bf16) @ Wc2 (256x3 f32) + bc2
__global__ void final_fc(const ushort* __restrict__ h2,
                         const float* __restrict__ wc2,
                         const float* __restrict__ bc2,
                         float* __restrict__ out) {
    __shared__ float w[768];
    int t = threadIdx.x;
    for (int i = t; i < 768; i += 256) w[i] = wc2[i];
    __syncthreads();
    int g = t >> 4, l = t & 15;
    int row = blockIdx.x * 16 + g;
    const ushort* hr = h2 + (size_t)row * 256 + l * 16;
    bf16x8 v0 = *reinterpret_cast<const bf16x8*>(hr);
    bf16x8 v1 = *reinterpret_cast<const bf16x8*>(hr + 8);
    float s0 = 0.f, s1 = 0.f, s2 = 0.f;
#pragma unroll
    for (int k = 0; k < 8; k++) {
        float h = bf2f((ushort)v0[k]);
        int c = (l * 16 + k) * 3;
        s0 += h * w[c]; s1 += h * w[c + 1]; s2 += h * w[c + 2];
    }
#pragma unroll
    for (int k = 0; k < 8; k++) {
        float h = bf2f((ushort)v1[k]);
        int c = (l * 16 + 8 + k) * 3;
        s0 += h * w[c]; s1 += h * w[c + 1]; s2 += h * w[c + 2];
    }
#pragma unroll
    for (int m = 1; m < 16; m <<= 1) {
        s0 += __shfl_xor(s0, m);
        s1 += __shfl_xor(s1, m);
        s2 += __shfl_xor(s2, m);
    }
    if (l == 0) {
        out[row * 3 + 0] = s0 + bc2[0];
        out[row * 3 + 1] = s1 + bc2[1];
        out[row * 3 + 2] = s2 + bc2[2];
    }
}

extern "C" void kernel_launch(void* const* d_in, const int* in_sizes, int n_in,
                              void* d_out, int out_size, void* d_ws, size_t ws_size,
                              hipStream_t stream) {
    (void)in_sizes; (void)n_in; (void)out_size; (void)ws_size;
    const float* xs = (const float*)d_in[0];
    const float* xo = (const float*)d_in[1];
    const float* xu = (const float*)d_in[2];
    const float* boxes = (const float*)d_in[3];
    const float* im_info = (const float*)d_in[4];
    const int* o1 = (const int*)d_in[5];
    const int* o2 = (const int*)d_in[6];
    const int* uu = (const int*)d_in[7];
    const int* im = (const int*)d_in[8];
    const float* Ws1 = (const float*)d_in[9];
    const float* bs1 = (const float*)d_in[10];
    const float* Ws2 = (const float*)d_in[11];
    const float* bs2 = (const float*)d_in[12];
    const float* Wo1 = (const float*)d_in[13];
    const float* bo1 = (const float*)d_in[14];
    const float* Wo2 = (const float*)d_in[15];
    const float* bo2 = (const float*)d_in[16];
    const float* Wu1 = (const float*)d_in[17];
    const float* bu1 = (const float*)d_in[18];
    const float* Wu2 = (const float*)d_in[19];
    const float* bu2 = (const float*)d_in[20];
    const float* Wc1 = (const float*)d_in[21];
    const float* bc1 = (const float*)d_in[22];
    const float* Wc2 = (const float*)d_in[23];
    const float* bc2 = (const float*)d_in[24];
    float* out = (float*)d_out;

    ushort* W1T = (ushort*)d_ws;                      // 3 * 512*2048
    ushort* H2BR = W1T;                               // alias (used after gemm1 is done with W1T)
    ushort* W2T = W1T + (size_t)3 * 512 * 2048;       // 3 * 256*512
    ushort* WC1T = W2T + (size_t)3 * 256 * 512;       // 256*288
    ushort* H1 = WC1T + (size_t)256 * 288;            // 3 * 3840*512
    ushort* HIN = H1 + (size_t)3 * 3840 * 512;        // 3840*288
    ushort* H2 = HIN + (size_t)3840 * 288;            // 3840*256
    float* PART = (float*)(H2 + (size_t)3840 * 256);  // 2 * 3*3840*512 f32 (47 MB)

    transpose_convert<<<dim3(32, 8, 3), 256, 0, stream>>>(Ws1, Wo1, Wu1, W1T, 2048, 512, 2048);
    transpose_convert2<<<dim3(8, 4, 4), 256, 0, stream>>>(Ws2, Wo2, Wu2, Wc1, W2T, WC1T);
    gemm1_main<<<720, 256, 0, stream>>>(xs, xo, xu, W1T, PART);
    reduce_h1<<<2880, 256, 0, stream>>>(PART, bs1, bo1, bu1, H1);
    gemm2<<<360, 256, 0, stream>>>(H1, W2T, bs2, bo2, bu2, H2BR);
    appear_pack<<<480, 256, 0, stream>>>(H2BR, HIN, boxes, im_info, o1, o2, uu, im);
    gemm3<<<dim3(60, 2), 256, 0, stream>>>(HIN, WC1T, bc1, H2);
    final_fc<<<240, 256, 0, stream>>>(H2, Wc2, bc2, out);
}

// Round 9
// 111.945 us; speedup vs baseline: 1.2258x; 1.2258x over previous
//
#include <hip/hip_runtime.h>

#define N_PAIR 3840

typedef short bf16x8 __attribute__((ext_vector_type(8)));
typedef float f32x4 __attribute__((ext_vector_type(4)));

static __device__ __forceinline__ ushort f2bf(float f) {
    uint x = __float_as_uint(f);
    uint r = (x + 0x7FFFu + ((x >> 16) & 1u)) >> 16;
    return (ushort)r;
}
static __device__ __forceinline__ float bf2f(ushort u) {
    return __uint_as_float(((uint)u) << 16);
}

// async global->LDS, 16B per lane; LDS dest is lane-linear (base + lane*16)
#define GLOAD16(GP, LP)                                                        \
    __builtin_amdgcn_global_load_lds(                                          \
        (const __attribute__((address_space(1))) void*)(GP),                   \
        (__attribute__((address_space(3))) void*)(LP), 16, 0, 0)

// 8 f32 -> bf16x8 via v_cvt_pk_bf16_f32 (RNE)
static __device__ __forceinline__ bf16x8 cvt8(float4 lo, float4 hi4) {
    union { bf16x8 v; uint u[4]; } r;
    asm("v_cvt_pk_bf16_f32 %0, %1, %2" : "=v"(r.u[0]) : "v"(lo.x), "v"(lo.y));
    asm("v_cvt_pk_bf16_f32 %0, %1, %2" : "=v"(r.u[1]) : "v"(lo.z), "v"(lo.w));
    asm("v_cvt_pk_bf16_f32 %0, %1, %2" : "=v"(r.u[2]) : "v"(hi4.x), "v"(hi4.y));
    asm("v_cvt_pk_bf16_f32 %0, %1, %2" : "=v"(r.u[3]) : "v"(hi4.z), "v"(hi4.w));
    return r.v;
}

// ---------------- transpose + convert: in (K,N) f32 -> out (N,Kpad) bf16, zero-padded
__global__ void transpose_convert(const float* __restrict__ in0,
                                  const float* __restrict__ in1,
                                  const float* __restrict__ in2,
                                  ushort* __restrict__ out,
                                  int K, int N, int Kpad) {
    const float* in = (blockIdx.z == 0) ? in0 : (blockIdx.z == 1 ? in1 : in2);
    ushort* o = out + (size_t)blockIdx.z * N * Kpad;
    __shared__ float tile[64][65];
    int k0 = blockIdx.x * 64, n0 = blockIdx.y * 64;
    int t = threadIdx.x;
    int r = t >> 2, c4 = (t & 3) * 16;
#pragma unroll
    for (int i = 0; i < 16; i++) {
        int k = k0 + r, n = n0 + c4 + i;
        tile[r][c4 + i] = (k < K && n < N) ? in[(size_t)k * N + n] : 0.f;
    }
    __syncthreads();
#pragma unroll
    for (int i = 0; i < 16; i++) {
        int n = n0 + r, k = k0 + c4 + i;
        if (n < N && k < Kpad) o[(size_t)n * Kpad + k] = f2bf(tile[c4 + i][r]);
    }
}

// W2 (z=0..2) + Wc1 (z=3) in one launch
__global__ void transpose_convert2(const float* __restrict__ Ws2,
                                   const float* __restrict__ Wo2,
                                   const float* __restrict__ Wu2,
                                   const float* __restrict__ Wc1,
                                   ushort* __restrict__ W2T,
                                   ushort* __restrict__ WC1T) {
    int z = blockIdx.z;
    const float* in; ushort* o; int K, N, Kpad;
    if (z < 3) {
        in = (z == 0) ? Ws2 : (z == 1 ? Wo2 : Wu2);
        o = W2T + (size_t)z * 256 * 512; K = 512; N = 256; Kpad = 512;
    } else {
        in = Wc1; o = WC1T; K = 275; N = 256; Kpad = 288;
    }
    __shared__ float tile[64][65];
    int k0 = blockIdx.x * 64, n0 = blockIdx.y * 64;
    int t = threadIdx.x;
    int r = t >> 2, c4 = (t & 3) * 16;
#pragma unroll
    for (int i = 0; i < 16; i++) {
        int k = k0 + r, n = n0 + c4 + i;
        tile[r][c4 + i] = (k < K && n < N) ? in[(size_t)k * N + n] : 0.f;
    }
    __syncthreads();
#pragma unroll
    for (int i = 0; i < 16; i++) {
        int n = n0 + r, k = k0 + c4 + i;
        if (n < N && k < Kpad) o[(size_t)n * Kpad + k] = f2bf(tile[c4 + i][r]);
    }
}

// ---------------- LDS helpers: 128B rows (BK=64 bf16), XOR swizzle
__device__ __forceinline__ bf16x8 frag_ld(const ushort* __restrict__ lds, int row, int colbyte) {
    int off = (row << 7) + (colbyte ^ ((row & 7) << 4));
    return *reinterpret_cast<const bf16x8*>(reinterpret_cast<const char*>(lds) + off);
}
// 64B rows (BK=32)
__device__ __forceinline__ bf16x8 frag32_ld(const ushort* __restrict__ lds, int row, int colbyte) {
    int off = (row << 6) + (colbyte ^ ((row & 3) << 4));
    return *reinterpret_cast<const bf16x8*>(reinterpret_cast<const char*>(lds) + off);
}

// ---------------- GEMM1 main: partial x @ W1t over half of K -> f32 partials
// BM=128 BN=128 BK=64, 4 waves (2x2); BOTH operands via global_load_lds w16
// (A kept f32 in LDS, converted in fragment path via v_cvt_pk_bf16_f32);
// single 48KB LDS buffer -> 3 blocks/CU; split-K=2 -> 720 blocks; m97 2-barrier loop.
__global__ __launch_bounds__(256) void gemm1_main(const float* __restrict__ xs,
                                                  const float* __restrict__ xo,
                                                  const float* __restrict__ xu,
                                                  const ushort* __restrict__ w1t,
                                                  float* __restrict__ part) {
    // 720 = 8 XCDs x 90; within chunk: (nt,ks) fastest -> same-mt blocks adjacent
    int bid = blockIdx.x;
    int w = (bid & 7) * 90 + (bid >> 3);
    int br = w / 240; int r = w - br * 240;
    int mt = r >> 3, nt = (r >> 1) & 3, ks = r & 1;

    const float* x = br == 0 ? xs : (br == 1 ? xo : xu);
    const ushort* wt = w1t + (size_t)br * 512 * 2048;
    float* out = part + ((size_t)(ks * 3 + br)) * 3840 * 512;

    __shared__ float Af[128 * 64];   // 32KB, f32, swizzled granules
    __shared__ ushort Bs[128 * 64];  // 16KB, bf16, swizzled granules
    int t = threadIdx.x, lane = t & 63, wid = t >> 6;
    int wr = wid >> 1, wc = wid & 1;
    int m0 = mt * 128, n0 = nt * 128, k0 = ks * 1024;
    const float* asrc = x + (size_t)m0 * 2048 + k0;
    const ushort* bsrc = wt + (size_t)n0 * 2048 + k0;
    int hi = lane >> 4, l15 = lane & 15;

    // Per-thread staging addresses (source pre-swizzled, LDS dest lane-linear).
    // A: granule g=(wid*8+i)*64+lane: row=(wid*8+i)*4+(lane>>4), c16=lane&15
    // B: granule g=(wid*4+i)*64+lane: row=(wid*4+i)*8+(lane>>3), c8=lane&7
    const float* aptr[8];
    const ushort* bptr[4];
#pragma unroll
    for (int i = 0; i < 8; i++) {
        int row = (wid * 8 + i) * 4 + (lane >> 4);
        int c16 = (lane & 15) ^ (row & 15);
        aptr[i] = asrc + (size_t)row * 2048 + (c16 << 2);
    }
#pragma unroll
    for (int i = 0; i < 4; i++) {
        int row = (wid * 4 + i) * 8 + (lane >> 3);
        int c8 = (lane & 7) ^ (row & 7);
        bptr[i] = bsrc + (size_t)row * 2048 + (c8 << 3);
    }

    f32x4 acc[4][4] = {};
    // prologue loads for kt=0
#pragma unroll
    for (int i = 0; i < 8; i++) GLOAD16(aptr[i], &Af[((wid * 8 + i) * 64 + lane) * 4]);
#pragma unroll
    for (int i = 0; i < 4; i++) GLOAD16(bptr[i], &Bs[((wid * 4 + i) * 64 + lane) * 8]);
    __syncthreads();

    for (int kt = 0; kt < 1024; kt += 64) {
        // MFMA phase from current buffer
#pragma unroll
        for (int kk = 0; kk < 64; kk += 32) {
            int kf = kk + hi * 8;      // frag k-origin for this lane
            int c0 = kf >> 2;          // even f32-granule index
            bf16x8 a[4], b[4];
#pragma unroll
            for (int i = 0; i < 4; i++) {
                int ra = wr * 64 + i * 16 + l15;
                const char* ab = reinterpret_cast<const char*>(&Af[0]);
                float4 lo = *reinterpret_cast<const float4*>(ab + ra * 256 + ((c0 ^ (ra & 15)) << 4));
                float4 h4 = *reinterpret_cast<const float4*>(ab + ra * 256 + (((c0 + 1) ^ (ra & 15)) << 4));
                a[i] = cvt8(lo, h4);
            }
#pragma unroll
            for (int j = 0; j < 4; j++)
                b[j] = frag_ld(&Bs[0], wc * 64 + j * 16 + l15, kf << 1);
#pragma unroll
            for (int i = 0; i < 4; i++)
#pragma unroll
                for (int j = 0; j < 4; j++)
                    acc[i][j] = __builtin_amdgcn_mfma_f32_16x16x32_bf16(a[i], b[j], acc[i][j], 0, 0, 0);
        }
        __syncthreads();  // all waves done reading buffer
        if (kt + 64 < 1024) {
#pragma unroll
            for (int i = 0; i < 8; i++) GLOAD16(aptr[i] + kt + 64, &Af[((wid * 8 + i) * 64 + lane) * 4]);
#pragma unroll
            for (int i = 0; i < 4; i++) GLOAD16(bptr[i] + kt + 64, &Bs[((wid * 4 + i) * 64 + lane) * 8]);
            __syncthreads();  // drain loads
        }
    }
    // store f32 partials
    int rb = m0 + wr * 64 + (hi << 2);
    int cb0 = n0 + wc * 64 + l15;
#pragma unroll
    for (int j = 0; j < 4; j++) {
        int col = cb0 + j * 16;
#pragma unroll
        for (int i = 0; i < 4; i++)
#pragma unroll
            for (int q = 0; q < 4; q++)
                out[(size_t)(rb + i * 16 + q) * 512 + col] = acc[i][j][q];
    }
}

// ---------------- reduce: H1 = relu(part0 + part1 + b1) -> bf16
__global__ void reduce_h1(const float* __restrict__ part,
                          const float* __restrict__ bs1,
                          const float* __restrict__ bo1,
                          const float* __restrict__ bu1,
                          ushort* __restrict__ h1) {
    const size_t D = (size_t)3840 * 512;
    size_t e = ((size_t)blockIdx.x * 256 + threadIdx.x) * 8;
    if (e >= 3 * D) return;
    int br = (int)(e / D);
    int col = (int)(e & 511);
    const float* bias = br == 0 ? bs1 : (br == 1 ? bo1 : bu1);
    const float4* p0 = reinterpret_cast<const float4*>(part + e);
    const float4* p1 = reinterpret_cast<const float4*>(part + 3 * D + e);
    const float4* bp = reinterpret_cast<const float4*>(bias + col);
    float4 a0 = p0[0], a1 = p0[1];
    float4 b0 = p1[0], b1 = p1[1];
    float4 c0 = bp[0], c1 = bp[1];
    union { bf16x8 v; ushort us[8]; } r;
#pragma unroll
    for (int i = 0; i < 4; i++) {
        float v = a0[i] + b0[i] + c0[i];
        r.us[i] = f2bf(v > 0.f ? v : 0.f);
        float w = a1[i] + b1[i] + c1[i];
        r.us[4 + i] = f2bf(w > 0.f ? w : 0.f);
    }
    *reinterpret_cast<bf16x8*>(h1 + e) = r.v;
}

// ---------------- GEMM2: h2br = relu(h1 @ W2t + b2) -> bf16 3x3840x256
// BM=64 BN=128 BK=64; BOTH operands via global_load_lds w16, pre-swizzled source.
__global__ __launch_bounds__(256) void gemm2(const ushort* __restrict__ h1,
                                             const ushort* __restrict__ w2t,
                                             const float* __restrict__ b_s,
                                             const float* __restrict__ b_o,
                                             const float* __restrict__ b_u,
                                             ushort* __restrict__ h2br) {
    // 360 blocks = 8 x 45, y fastest
    int bid = blockIdx.x;
    int w = (bid & 7) * 45 + (bid >> 3);
    int br = w / 120; int r = w - br * 120;
    int xt = r >> 1, yt = r & 1;

    const ushort* A = h1 + (size_t)br * 3840 * 512;
    const ushort* B = w2t + (size_t)br * 256 * 512;
    const float* bias = br == 0 ? b_s : (br == 1 ? b_o : b_u);
    ushort* out = h2br + (size_t)br * 3840 * 256;

    __shared__ ushort As[2][64 * 64];
    __shared__ ushort Bs[2][128 * 64];
    int t = threadIdx.x, lane = t & 63, wid = t >> 6;
    int wr = wid >> 1, wc = wid & 1;
    int m0 = xt * 64, n0 = yt * 128;
    const ushort* asrc = A + (size_t)m0 * 512;
    const ushort* bsrc = B + (size_t)n0 * 512;

#define G2_GLOADS(BUF, KT)                                                                \
    {                                                                                     \
        _Pragma("unroll")                                                                 \
        for (int it = 0; it < 2; it++) {                                                  \
            int g = (wid * 2 + it) * 64 + lane;                                           \
            int rr = g >> 3, cc = g & 7;                                                  \
            const ushort* gp = asrc + (size_t)rr * 512 + (KT) + ((cc ^ (rr & 7)) << 3);   \
            GLOAD16(gp, &As[BUF][g * 8]);                                                 \
        }                                                                                 \
        _Pragma("unroll")                                                                 \
        for (int it = 0; it < 4; it++) {                                                  \
            int g = (wid * 4 + it) * 64 + lane;                                           \
            int rr = g >> 3, cc = g & 7;                                                  \
            const ushort* gp = bsrc + (size_t)rr * 512 + (KT) + ((cc ^ (rr & 7)) << 3);   \
            GLOAD16(gp, &Bs[BUF][g * 8]);                                                 \
        }                                                                                 \
    }
#define G2_MFMA(BUF)                                                                      \
    _Pragma("unroll")                                                                     \
    for (int kk = 0; kk < 64; kk += 32) {                                                 \
        int cb = (kk + ((lane >> 4) << 3)) << 1;                                          \
        bf16x8 a[2], b[4];                                                                \
        _Pragma("unroll")                                                                 \
        for (int i = 0; i < 2; i++) a[i] = frag_ld(&As[BUF][0], wr * 32 + i * 16 + (lane & 15), cb); \
        _Pragma("unroll")                                                                 \
        for (int f = 0; f < 4; f++) b[f] = frag_ld(&Bs[BUF][0], wc * 64 + f * 16 + (lane & 15), cb); \
        _Pragma("unroll")                                                                 \
        for (int i = 0; i < 2; i++)                                                       \
            _Pragma("unroll")                                                             \
            for (int j = 0; j < 4; j++)                                                   \
                acc[i][j] = __builtin_amdgcn_mfma_f32_16x16x32_bf16(a[i], b[j], acc[i][j], 0, 0, 0); \
    }

    f32x4 acc[2][4] = {};
    G2_GLOADS(0, 0)
    __syncthreads();
    int cur = 0;
    for (int kt = 0; kt < 512; kt += 64) {
        if (kt + 64 < 512) G2_GLOADS(cur ^ 1, kt + 64)
        G2_MFMA(cur)
        __syncthreads();
        cur ^= 1;
    }
    int rb = m0 + wr * 32 + ((lane >> 4) << 2);
    int cb0 = n0 + wc * 64 + (lane & 15);
#pragma unroll
    for (int j = 0; j < 4; j++) {
        int col = cb0 + j * 16;
        float bv = bias[col];
#pragma unroll
        for (int i = 0; i < 2; i++)
#pragma unroll
            for (int q = 0; q < 4; q++) {
                int row = rb + i * 16 + q;
                float v = acc[i][j][q] + bv;
                v = v > 0.f ? v : 0.f;
                out[(size_t)row * 256 + col] = f2bf(v);
            }
    }
#undef G2_GLOADS
#undef G2_MFMA
}

// ---------------- appear = u - o - s -> hin[:,0:256); loc features -> hin[:,256:288)
__global__ void appear_pack(const ushort* __restrict__ h2br,
                            ushort* __restrict__ hin,
                            const float* __restrict__ boxes,
                            const float* __restrict__ im_info,
                            const int* __restrict__ o1, const int* __restrict__ o2,
                            const int* __restrict__ u, const int* __restrict__ im) {
    int i = blockIdx.x * 256 + threadIdx.x;
    if (i < N_PAIR * 32) {
        int p = i >> 5, ch = (i & 31) * 8;
        const ushort* ps = h2br + (size_t)p * 256 + ch;
        bf16x8 vs = *reinterpret_cast<const bf16x8*>(ps);
        bf16x8 vo = *reinterpret_cast<const bf16x8*>(ps + (size_t)3840 * 256);
        bf16x8 vu = *reinterpret_cast<const bf16x8*>(ps + (size_t)2 * 3840 * 256);
        union { bf16x8 v; ushort us[8]; } r;
#pragma unroll
        for (int j = 0; j < 8; j++)
            r.us[j] = f2bf(bf2f(((ushort)vu[j])) - bf2f(((ushort)vo[j])) - bf2f(((ushort)vs[j])));
        *reinterpret_cast<bf16x8*>(hin + (size_t)p * 288 + ch) = r.v;
    }
    if (blockIdx.x < 15) {
        int p = blockIdx.x * 256 + threadIdx.x;
        const float* sb = boxes + 5 * o1[p] + 1;
        const float* ob = boxes + 5 * o2[p] + 1;
        const float* ub = boxes + 5 * u[p] + 1;
        const float* ii = im_info + 3 * im[p];
        float hi = ii[0], wi = ii[1];
        float x_s = (sb[0] + sb[2]) * 0.5f, y_s = (sb[1] + sb[3]) * 0.5f;
        float w_s = sb[2] - sb[0], h_s = sb[3] - sb[1];
        float x_o = (ob[0] + ob[2]) * 0.5f, y_o = (ob[1] + ob[3]) * 0.5f;
        float w_o = ob[2] - ob[0], h_o = ob[3] - ob[1];
        float a_s = w_s * h_s, a_o = w_o * h_o;
        float a_u = (ub[2] - ub[0]) * (ub[3] - ub[1]);
        float area = wi * hi;
        float f[19];
        f[0] = x_s / wi;            f[1] = y_s / hi;
        f[2] = (x_s + w_s) / wi;    f[3] = (y_s + h_s) / hi;
        f[4] = a_s / area;
        f[5] = x_o / wi;            f[6] = y_o / hi;
        f[7] = (x_o + w_o) / wi;    f[8] = (y_o + h_o) / hi;
        f[9] = a_o / area;
        f[10] = (x_s - x_o) / w_o;  f[11] = (y_s - y_o) / h_o;
        f[12] = logf(w_s / w_o);    f[13] = logf(h_s / h_o);
        f[14] = (x_o - x_s) / w_s;  f[15] = (y_o - y_s) / h_s;
        f[16] = logf(w_o / w_s);    f[17] = logf(h_o / h_s);
        f[18] = a_u / area;
        ushort* row = hin + (size_t)p * 288 + 256;
#pragma unroll
        for (int k = 0; k < 19; k++) row[k] = f2bf(f[k]);
#pragma unroll
        for (int k = 19; k < 32; k++) row[k] = 0;
    }
}

// ---------------- GEMM3: h2 = relu(hin (3840x288) @ Wc1t + bc1) -> bf16 3840x256
__global__ __launch_bounds__(256) void gemm3(const ushort* __restrict__ hin,
                                             const ushort* __restrict__ wc1t,
                                             const float* __restrict__ bc1,
                                             ushort* __restrict__ h2) {
    __shared__ ushort As[2][64 * 32];
    __shared__ ushort Bs[2][128 * 32];
    int t = threadIdx.x, lane = t & 63, wid = t >> 6;
    int wr = wid >> 1, wc = wid & 1;
    int m0 = blockIdx.x * 64, n0 = blockIdx.y * 128;
    const ushort* asrc = hin + (size_t)m0 * 288;
    const ushort* bsrc = wc1t + (size_t)n0 * 288;

    int ar = t >> 2, ac = (t & 3) * 8;
    bf16x8 pa, pb[2];
    auto issue = [&](int kt) {
        pa = *reinterpret_cast<const bf16x8*>(asrc + (size_t)ar * 288 + kt + ac);
#pragma unroll
        for (int it = 0; it < 2; it++) {
            int e = (it * 256 + t) * 8;
            int rr = e >> 5, cc = e & 31;
            pb[it] = *reinterpret_cast<const bf16x8*>(bsrc + (size_t)rr * 288 + kt + cc);
        }
    };
    auto commit = [&](int buf) {
        char* ab = reinterpret_cast<char*>(&As[buf][0]);
        int off0 = (ar << 6) + ((ac << 1) ^ ((ar & 3) << 4));
        *reinterpret_cast<bf16x8*>(ab + off0) = pa;
        char* bb = reinterpret_cast<char*>(&Bs[buf][0]);
#pragma unroll
        for (int it = 0; it < 2; it++) {
            int e = (it * 256 + t) * 8;
            int rr = e >> 5, cc = e & 31;
            int off = (rr << 6) + ((cc << 1) ^ ((rr & 3) << 4));
            *reinterpret_cast<bf16x8*>(bb + off) = pb[it];
        }
    };

    f32x4 acc[2][4] = {};
    issue(0);
    commit(0);
    __syncthreads();
    int cur = 0;
    for (int kt = 0; kt < 288; kt += 32) {
        int nxt = kt + 32;
        if (nxt < 288) issue(nxt);
        int cb = ((lane >> 4) << 3) << 1;
        bf16x8 a[2], b[4];
#pragma unroll
        for (int i = 0; i < 2; i++) a[i] = frag32_ld(&As[cur][0], wr * 32 + i * 16 + (lane & 15), cb);
#pragma unroll
        for (int f = 0; f < 4; f++) b[f] = frag32_ld(&Bs[cur][0], wc * 64 + f * 16 + (lane & 15), cb);
#pragma unroll
        for (int i = 0; i < 2; i++)
#pragma unroll
            for (int j = 0; j < 4; j++)
                acc[i][j] = __builtin_amdgcn_mfma_f32_16x16x32_bf16(a[i], b[j], acc[i][j], 0, 0, 0);
        if (nxt < 288) commit(cur ^ 1);
        __syncthreads();
        cur ^= 1;
    }
    int rb = m0 + wr * 32 + ((lane >> 4) << 2);
    int cb0 = n0 + wc * 64 + (lane & 15);
#pragma unroll
    for (int j = 0; j < 4; j++) {
        int col = cb0 + j * 16;
        float bv = bc1[col];
#pragma unroll
        for (int i = 0; i < 2; i++)
#pragma unroll
            for (int q = 0; q < 4; q++) {
                int row = rb + i * 16 + q;
                float v = acc[i][j][q] + bv;
                v = v > 0.f ? v : 0.f;
                h2[(size_t)row * 256 + col] = f2bf(v);
            }
    }
}

// ---------------- final: out = h2 (3840x256 bf16) @ Wc2 (256x3 f32) + bc2
__global__ void final_fc(const ushort* __restrict__ h2,
                         const float* __restrict__ wc2,
                         const float* __restrict__ bc2,
                         float* __restrict__ out) {
    __shared__ float w[768];
    int t = threadIdx.x;
    for (int i = t; i < 768; i += 256) w[i] = wc2[i];
    __syncthreads();
    int g = t >> 4, l = t & 15;
    int row = blockIdx.x * 16 + g;
    const ushort* hr = h2 + (size_t)row * 256 + l * 16;
    bf16x8 v0 = *reinterpret_cast<const bf16x8*>(hr);
    bf16x8 v1 = *reinterpret_cast<const bf16x8*>(hr + 8);
    float s0 = 0.f, s1 = 0.f, s2 = 0.f;
#pragma unroll
    for (int k = 0; k < 8; k++) {
        float h = bf2f((ushort)v0[k]);
        int c = (l * 16 + k) * 3;
        s0 += h * w[c]; s1 += h * w[c + 1]; s2 += h * w[c + 2];
    }
#pragma unroll
    for (int k = 0; k < 8; k++) {
        float h = bf2f((ushort)v1[k]);
        int c = (l * 16 + 8 + k) * 3;
        s0 += h * w[c]; s1 += h * w[c + 1]; s2 += h * w[c + 2];
    }
#pragma unroll
    for (int m = 1; m < 16; m <<= 1) {
        s0 += __shfl_xor(s0, m);
        s1 += __shfl_xor(s1, m);
        s2 += __shfl_xor(s2, m);
    }
    if (l == 0) {
        out[row * 3 + 0] = s0 + bc2[0];
        out[row * 3 + 1] = s1 + bc2[1];
        out[row * 3 + 2] = s2 + bc2[2];
    }
}

extern "C" void kernel_launch(void* const* d_in, const int* in_sizes, int n_in,
                              void* d_out, int out_size, void* d_ws, size_t ws_size,
                              hipStream_t stream) {
    (void)in_sizes; (void)n_in; (void)out_size; (void)ws_size;
    const float* xs = (const float*)d_in[0];
    const float* xo = (const float*)d_in[1];
    const float* xu = (const float*)d_in[2];
    const float* boxes = (const float*)d_in[3];
    const float* im_info = (const float*)d_in[4];
    const int* o1 = (const int*)d_in[5];
    const int* o2 = (const int*)d_in[6];
    const int* uu = (const int*)d_in[7];
    const int* im = (const int*)d_in[8];
    const float* Ws1 = (const float*)d_in[9];
    const float* bs1 = (const float*)d_in[10];
    const float* Ws2 = (const float*)d_in[11];
    const float* bs2 = (const float*)d_in[12];
    const float* Wo1 = (const float*)d_in[13];
    const float* bo1 = (const float*)d_in[14];
    const float* Wo2 = (const float*)d_in[15];
    const float* bo2 = (const float*)d_in[16];
    const float* Wu1 = (const float*)d_in[17];
    const float* bu1 = (const float*)d_in[18];
    const float* Wu2 = (const float*)d_in[19];
    const float* bu2 = (const float*)d_in[20];
    const float* Wc1 = (const float*)d_in[21];
    const float* bc1 = (const float*)d_in[22];
    const float* Wc2 = (const float*)d_in[23];
    const float* bc2 = (const float*)d_in[24];
    float* out = (float*)d_out;

    ushort* W1T = (ushort*)d_ws;                      // 3 * 512*2048
    ushort* H2BR = W1T;                               // alias (used after gemm1 is done with W1T)
    ushort* W2T = W1T + (size_t)3 * 512 * 2048;       // 3 * 256*512
    ushort* WC1T = W2T + (size_t)3 * 256 * 512;       // 256*288
    ushort* H1 = WC1T + (size_t)256 * 288;            // 3 * 3840*512
    ushort* HIN = H1 + (size_t)3 * 3840 * 512;        // 3840*288
    ushort* H2 = HIN + (size_t)3840 * 288;            // 3840*256
    float* PART = (float*)(H2 + (size_t)3840 * 256);  // 2 * 3*3840*512 f32 (47 MB)

    transpose_convert<<<dim3(32, 8, 3), 256, 0, stream>>>(Ws1, Wo1, Wu1, W1T, 2048, 512, 2048);
    transpose_convert2<<<dim3(8, 4, 4), 256, 0, stream>>>(Ws2, Wo2, Wu2, Wc1, W2T, WC1T);
    gemm1_main<<<720, 256, 0, stream>>>(xs, xo, xu, W1T, PART);
    reduce_h1<<<2880, 256, 0, stream>>>(PART, bs1, bo1, bu1, H1);
    gemm2<<<360, 256, 0, stream>>>(H1, W2T, bs2, bo2, bu2, H2BR);
    appear_pack<<<480, 256, 0, stream>>>(H2BR, HIN, boxes, im_info, o1, o2, uu, im);
    gemm3<<<dim3(60, 2), 256, 0, stream>>>(HIN, WC1T, bc1, H2);
    final_fc<<<240, 256, 0, stream>>>(H2, Wc2, bc2, out);
}

// Round 10
// 105.871 us; speedup vs baseline: 1.2961x; 1.0574x over previous
//
#include <hip/hip_runtime.h>

#define N_PAIR 3840

typedef short bf16x8 __attribute__((ext_vector_type(8)));
typedef float f32x4 __attribute__((ext_vector_type(4)));

static __device__ __forceinline__ ushort f2bf(float f) {
    uint x = __float_as_uint(f);
    uint r = (x + 0x7FFFu + ((x >> 16) & 1u)) >> 16;
    return (ushort)r;
}
static __device__ __forceinline__ float bf2f(ushort u) {
    return __uint_as_float(((uint)u) << 16);
}

// async global->LDS, 16B per lane; LDS dest is lane-linear (base + lane*16)
#define GLOAD16(GP, LP)                                                        \
    __builtin_amdgcn_global_load_lds(                                          \
        (const __attribute__((address_space(1))) void*)(GP),                   \
        (__attribute__((address_space(3))) void*)(LP), 16, 0, 0)

// 8 f32 -> bf16x8 via v_cvt_pk_bf16_f32 (RNE)
static __device__ __forceinline__ bf16x8 cvt8(float4 lo, float4 hi4) {
    union { bf16x8 v; uint u[4]; } r;
    asm("v_cvt_pk_bf16_f32 %0, %1, %2" : "=v"(r.u[0]) : "v"(lo.x), "v"(lo.y));
    asm("v_cvt_pk_bf16_f32 %0, %1, %2" : "=v"(r.u[1]) : "v"(lo.z), "v"(lo.w));
    asm("v_cvt_pk_bf16_f32 %0, %1, %2" : "=v"(r.u[2]) : "v"(hi4.x), "v"(hi4.y));
    asm("v_cvt_pk_bf16_f32 %0, %1, %2" : "=v"(r.u[3]) : "v"(hi4.z), "v"(hi4.w));
    return r.v;
}

// ---------------- transpose + convert: in (K,N) f32 -> out (N,Kpad) bf16, zero-padded
__global__ void transpose_convert(const float* __restrict__ in0,
                                  const float* __restrict__ in1,
                                  const float* __restrict__ in2,
                                  ushort* __restrict__ out,
                                  int K, int N, int Kpad) {
    const float* in = (blockIdx.z == 0) ? in0 : (blockIdx.z == 1 ? in1 : in2);
    ushort* o = out + (size_t)blockIdx.z * N * Kpad;
    __shared__ float tile[64][65];
    int k0 = blockIdx.x * 64, n0 = blockIdx.y * 64;
    int t = threadIdx.x;
    int r = t >> 2, c4 = (t & 3) * 16;
#pragma unroll
    for (int i = 0; i < 16; i++) {
        int k = k0 + r, n = n0 + c4 + i;
        tile[r][c4 + i] = (k < K && n < N) ? in[(size_t)k * N + n] : 0.f;
    }
    __syncthreads();
#pragma unroll
    for (int i = 0; i < 16; i++) {
        int n = n0 + r, k = k0 + c4 + i;
        if (n < N && k < Kpad) o[(size_t)n * Kpad + k] = f2bf(tile[c4 + i][r]);
    }
}

// W2 (z=0..2) + Wc1 (z=3) in one launch
__global__ void transpose_convert2(const float* __restrict__ Ws2,
                                   const float* __restrict__ Wo2,
                                   const float* __restrict__ Wu2,
                                   const float* __restrict__ Wc1,
                                   ushort* __restrict__ W2T,
                                   ushort* __restrict__ WC1T) {
    int z = blockIdx.z;
    const float* in; ushort* o; int K, N, Kpad;
    if (z < 3) {
        in = (z == 0) ? Ws2 : (z == 1 ? Wo2 : Wu2);
        o = W2T + (size_t)z * 256 * 512; K = 512; N = 256; Kpad = 512;
    } else {
        in = Wc1; o = WC1T; K = 275; N = 256; Kpad = 288;
    }
    __shared__ float tile[64][65];
    int k0 = blockIdx.x * 64, n0 = blockIdx.y * 64;
    int t = threadIdx.x;
    int r = t >> 2, c4 = (t & 3) * 16;
#pragma unroll
    for (int i = 0; i < 16; i++) {
        int k = k0 + r, n = n0 + c4 + i;
        tile[r][c4 + i] = (k < K && n < N) ? in[(size_t)k * N + n] : 0.f;
    }
    __syncthreads();
#pragma unroll
    for (int i = 0; i < 16; i++) {
        int n = n0 + r, k = k0 + c4 + i;
        if (n < N && k < Kpad) o[(size_t)n * Kpad + k] = f2bf(tile[c4 + i][r]);
    }
}

// ---------------- LDS helpers: 128B rows (BK=64 bf16), XOR swizzle
__device__ __forceinline__ bf16x8 frag_ld(const ushort* __restrict__ lds, int row, int colbyte) {
    int off = (row << 7) + (colbyte ^ ((row & 7) << 4));
    return *reinterpret_cast<const bf16x8*>(reinterpret_cast<const char*>(lds) + off);
}
// 64B rows (BK=32)
__device__ __forceinline__ bf16x8 frag32_ld(const ushort* __restrict__ lds, int row, int colbyte) {
    int off = (row << 6) + (colbyte ^ ((row & 3) << 4));
    return *reinterpret_cast<const bf16x8*>(reinterpret_cast<const char*>(lds) + off);
}

// ---------------- GEMM1: h1[br] = relu(x (3840x2048 f32) @ W1t + b1) -> bf16 3840x512
// SINGLE-WAVE blocks (64 threads): wave tile 64x64, BK=32, barrier-FREE K-loop.
// Double-buffered LDS (24KB) with explicit counted s_waitcnt vmcnt(12): the next
// tile's 12 global_load_lds stay in flight across the MFMA phase. 6 independent
// wave-streams per CU hide L2/HBM latency (no barrier-locked waves anywhere).
__global__ __launch_bounds__(64) void gemm1(const float* __restrict__ xs,
                                            const float* __restrict__ xo,
                                            const float* __restrict__ xu,
                                            const ushort* __restrict__ w1t,
                                            const float* __restrict__ b_s,
                                            const float* __restrict__ b_o,
                                            const float* __restrict__ b_u,
                                            ushort* __restrict__ h1out) {
    // 1440 blocks = 8 XCDs x 180; nt fastest (A-strip-sharing blocks in one XCD)
    int bid = blockIdx.x;
    int w = (bid & 7) * 180 + (bid >> 3);
    int br = w / 480; int r = w - br * 480;
    int mt = r >> 3, nt = r & 7;

    const float* x = br == 0 ? xs : (br == 1 ? xo : xu);
    const ushort* wt = w1t + (size_t)br * 512 * 2048;
    const float* bias = br == 0 ? b_s : (br == 1 ? b_o : b_u);
    ushort* out = h1out + (size_t)br * 3840 * 512;

    __shared__ float Af[2][64 * 32];   // 8KB per buffer, f32, swizzled granules
    __shared__ ushort Bs[2][64 * 32];  // 4KB per buffer, bf16, swizzled granules
    int lane = threadIdx.x;
    int hi = lane >> 4, l15 = lane & 15;
    int m0 = mt * 64, n0 = nt * 64;
    const float* asrc = x + (size_t)m0 * 2048;
    const ushort* bsrc = wt + (size_t)n0 * 2048;

    // staging addresses: source pre-swizzled (involution), LDS dest lane-linear.
    // A granule g=i*64+lane: row=i*8+(lane>>3), c8=lane&7; content col-granule = c8^(row&7)=c8^(lane>>3)
    // B granule g=i*64+lane: row=i*16+(lane>>2), c4=lane&3; content col-granule = c4^((lane>>2)&3)
    const float* ap[8];
    const ushort* bp[4];
    {
        int acol = ((lane & 7) ^ (lane >> 3)) << 2;     // f32 elems
#pragma unroll
        for (int i = 0; i < 8; i++)
            ap[i] = asrc + (size_t)(i * 8 + (lane >> 3)) * 2048 + acol;
        int bcol = ((lane & 3) ^ ((lane >> 2) & 3)) << 3; // ushorts
#pragma unroll
        for (int i = 0; i < 4; i++)
            bp[i] = bsrc + (size_t)(i * 16 + (lane >> 2)) * 2048 + bcol;
    }

#define G1_STAGE(BUF, KT)                                                     \
    {                                                                         \
        _Pragma("unroll")                                                     \
        for (int i = 0; i < 8; i++)                                           \
            GLOAD16(ap[i] + (KT), &Af[BUF][(i * 64 + lane) * 4]);             \
        _Pragma("unroll")                                                     \
        for (int i = 0; i < 4; i++)                                           \
            GLOAD16(bp[i] + (KT), &Bs[BUF][(i * 64 + lane) * 8]);             \
    }

    f32x4 acc[4][4] = {};
    G1_STAGE(0, 0)
    G1_STAGE(1, 32)

    int c0 = hi * 2;  // lane's first f32 granule within the 8-granule A row window
    for (int kt = 0; kt < 2048; kt += 32) {
        int cur = (kt >> 5) & 1;
        if (kt < 2048 - 32) {
            // counted wait: completes THIS tile's 12 loads, leaves next tile's 12 in flight
            asm volatile("s_waitcnt vmcnt(12)" ::: "memory");
        } else {
            asm volatile("s_waitcnt vmcnt(0)" ::: "memory");
        }
        __builtin_amdgcn_sched_barrier(0);
        bf16x8 a[4], b[4];
#pragma unroll
        for (int i = 0; i < 4; i++) {
            int ra = i * 16 + l15;
            const char* ab = reinterpret_cast<const char*>(&Af[cur][0]);
            float4 lo = *reinterpret_cast<const float4*>(ab + ra * 128 + ((c0 ^ (ra & 7)) << 4));
            float4 h4 = *reinterpret_cast<const float4*>(ab + ra * 128 + (((c0 + 1) ^ (ra & 7)) << 4));
            a[i] = cvt8(lo, h4);
        }
#pragma unroll
        for (int j = 0; j < 4; j++) {
            int rb = j * 16 + l15;
            const char* bb = reinterpret_cast<const char*>(&Bs[cur][0]);
            b[j] = *reinterpret_cast<const bf16x8*>(bb + rb * 64 + ((hi ^ (rb & 3)) << 4));
        }
#pragma unroll
        for (int i = 0; i < 4; i++)
#pragma unroll
            for (int j = 0; j < 4; j++)
                acc[i][j] = __builtin_amdgcn_mfma_f32_16x16x32_bf16(a[i], b[j], acc[i][j], 0, 0, 0);
        if (kt + 64 < 2048) G1_STAGE(cur, kt + 64)  // refill the buffer just consumed
    }
    // epilogue: frag (i,j): row = m0+i*16+hi*4+q, col = n0+j*16+l15
    int rbase = m0 + (hi << 2);
    int cbase = n0 + l15;
#pragma unroll
    for (int j = 0; j < 4; j++) {
        int col = cbase + j * 16;
        float bv = bias[col];
#pragma unroll
        for (int i = 0; i < 4; i++)
#pragma unroll
            for (int q = 0; q < 4; q++) {
                int row = rbase + i * 16 + q;
                float v = acc[i][j][q] + bv;
                v = v > 0.f ? v : 0.f;
                out[(size_t)row * 512 + col] = f2bf(v);
            }
    }
#undef G1_STAGE
}

// ---------------- GEMM2: h2br = relu(h1 @ W2t + b2) -> bf16 3x3840x256
// BM=64 BN=128 BK=64; BOTH operands via global_load_lds w16, pre-swizzled source.
__global__ __launch_bounds__(256) void gemm2(const ushort* __restrict__ h1,
                                             const ushort* __restrict__ w2t,
                                             const float* __restrict__ b_s,
                                             const float* __restrict__ b_o,
                                             const float* __restrict__ b_u,
                                             ushort* __restrict__ h2br) {
    // 360 blocks = 8 x 45, y fastest
    int bid = blockIdx.x;
    int w = (bid & 7) * 45 + (bid >> 3);
    int br = w / 120; int r = w - br * 120;
    int xt = r >> 1, yt = r & 1;

    const ushort* A = h1 + (size_t)br * 3840 * 512;
    const ushort* B = w2t + (size_t)br * 256 * 512;
    const float* bias = br == 0 ? b_s : (br == 1 ? b_o : b_u);
    ushort* out = h2br + (size_t)br * 3840 * 256;

    __shared__ ushort As[2][64 * 64];
    __shared__ ushort Bs[2][128 * 64];
    int t = threadIdx.x, lane = t & 63, wid = t >> 6;
    int wr = wid >> 1, wc = wid & 1;
    int m0 = xt * 64, n0 = yt * 128;
    const ushort* asrc = A + (size_t)m0 * 512;
    const ushort* bsrc = B + (size_t)n0 * 512;

#define G2_GLOADS(BUF, KT)                                                                \
    {                                                                                     \
        _Pragma("unroll")                                                                 \
        for (int it = 0; it < 2; it++) {                                                  \
            int g = (wid * 2 + it) * 64 + lane;                                           \
            int rr = g >> 3, cc = g & 7;                                                  \
            const ushort* gp = asrc + (size_t)rr * 512 + (KT) + ((cc ^ (rr & 7)) << 3);   \
            GLOAD16(gp, &As[BUF][g * 8]);                                                 \
        }                                                                                 \
        _Pragma("unroll")                                                                 \
        for (int it = 0; it < 4; it++) {                                                  \
            int g = (wid * 4 + it) * 64 + lane;                                           \
            int rr = g >> 3, cc = g & 7;                                                  \
            const ushort* gp = bsrc + (size_t)rr * 512 + (KT) + ((cc ^ (rr & 7)) << 3);   \
            GLOAD16(gp, &Bs[BUF][g * 8]);                                                 \
        }                                                                                 \
    }
#define G2_MFMA(BUF)                                                                      \
    _Pragma("unroll")                                                                     \
    for (int kk = 0; kk < 64; kk += 32) {                                                 \
        int cb = (kk + ((lane >> 4) << 3)) << 1;                                          \
        bf16x8 a[2], b[4];                                                                \
        _Pragma("unroll")                                                                 \
        for (int i = 0; i < 2; i++) a[i] = frag_ld(&As[BUF][0], wr * 32 + i * 16 + (lane & 15), cb); \
        _Pragma("unroll")                                                                 \
        for (int f = 0; f < 4; f++) b[f] = frag_ld(&Bs[BUF][0], wc * 64 + f * 16 + (lane & 15), cb); \
        _Pragma("unroll")                                                                 \
        for (int i = 0; i < 2; i++)                                                       \
            _Pragma("unroll")                                                             \
            for (int j = 0; j < 4; j++)                                                   \
                acc[i][j] = __builtin_amdgcn_mfma_f32_16x16x32_bf16(a[i], b[j], acc[i][j], 0, 0, 0); \
    }

    f32x4 acc[2][4] = {};
    G2_GLOADS(0, 0)
    __syncthreads();
    int cur = 0;
    for (int kt = 0; kt < 512; kt += 64) {
        if (kt + 64 < 512) G2_GLOADS(cur ^ 1, kt + 64)
        G2_MFMA(cur)
        __syncthreads();
        cur ^= 1;
    }
    int rb = m0 + wr * 32 + ((lane >> 4) << 2);
    int cb0 = n0 + wc * 64 + (lane & 15);
#pragma unroll
    for (int j = 0; j < 4; j++) {
        int col = cb0 + j * 16;
        float bv = bias[col];
#pragma unroll
        for (int i = 0; i < 2; i++)
#pragma unroll
            for (int q = 0; q < 4; q++) {
                int row = rb + i * 16 + q;
                float v = acc[i][j][q] + bv;
                v = v > 0.f ? v : 0.f;
                out[(size_t)row * 256 + col] = f2bf(v);
            }
    }
#undef G2_GLOADS
#undef G2_MFMA
}

// ---------------- appear = u - o - s -> hin[:,0:256); loc features -> hin[:,256:288)
__global__ void appear_pack(const ushort* __restrict__ h2br,
                            ushort* __restrict__ hin,
                            const float* __restrict__ boxes,
                            const float* __restrict__ im_info,
                            const int* __restrict__ o1, const int* __restrict__ o2,
                            const int* __restrict__ u, const int* __restrict__ im) {
    int i = blockIdx.x * 256 + threadIdx.x;
    if (i < N_PAIR * 32) {
        int p = i >> 5, ch = (i & 31) * 8;
        const ushort* ps = h2br + (size_t)p * 256 + ch;
        bf16x8 vs = *reinterpret_cast<const bf16x8*>(ps);
        bf16x8 vo = *reinterpret_cast<const bf16x8*>(ps + (size_t)3840 * 256);
        bf16x8 vu = *reinterpret_cast<const bf16x8*>(ps + (size_t)2 * 3840 * 256);
        union { bf16x8 v; ushort us[8]; } r;
#pragma unroll
        for (int j = 0; j < 8; j++)
            r.us[j] = f2bf(bf2f(((ushort)vu[j])) - bf2f(((ushort)vo[j])) - bf2f(((ushort)vs[j])));
        *reinterpret_cast<bf16x8*>(hin + (size_t)p * 288 + ch) = r.v;
    }
    if (blockIdx.x < 15) {
        int p = blockIdx.x * 256 + threadIdx.x;
        const float* sb = boxes + 5 * o1[p] + 1;
        const float* ob = boxes + 5 * o2[p] + 1;
        const float* ub = boxes + 5 * u[p] + 1;
        const float* ii = im_info + 3 * im[p];
        float hi = ii[0], wi = ii[1];
        float x_s = (sb[0] + sb[2]) * 0.5f, y_s = (sb[1] + sb[3]) * 0.5f;
        float w_s = sb[2] - sb[0], h_s = sb[3] - sb[1];
        float x_o = (ob[0] + ob[2]) * 0.5f, y_o = (ob[1] + ob[3]) * 0.5f;
        float w_o = ob[2] - ob[0], h_o = ob[3] - ob[1];
        float a_s = w_s * h_s, a_o = w_o * h_o;
        float a_u = (ub[2] - ub[0]) * (ub[3] - ub[1]);
        float area = wi * hi;
        float f[19];
        f[0] = x_s / wi;            f[1] = y_s / hi;
        f[2] = (x_s + w_s) / wi;    f[3] = (y_s + h_s) / hi;
        f[4] = a_s / area;
        f[5] = x_o / wi;            f[6] = y_o / hi;
        f[7] = (x_o + w_o) / wi;    f[8] = (y_o + h_o) / hi;
        f[9] = a_o / area;
        f[10] = (x_s - x_o) / w_o;  f[11] = (y_s - y_o) / h_o;
        f[12] = logf(w_s / w_o);    f[13] = logf(h_s / h_o);
        f[14] = (x_o - x_s) / w_s;  f[15] = (y_o - y_s) / h_s;
        f[16] = logf(w_o / w_s);    f[17] = logf(h_o / h_s);
        f[18] = a_u / area;
        ushort* row = hin + (size_t)p * 288 + 256;
#pragma unroll
        for (int k = 0; k < 19; k++) row[k] = f2bf(f[k]);
#pragma unroll
        for (int k = 19; k < 32; k++) row[k] = 0;
    }
}

// ---------------- GEMM3: h2 = relu(hin (3840x288) @ Wc1t + bc1) -> bf16 3840x256
__global__ __launch_bounds__(256) void gemm3(const ushort* __restrict__ hin,
                                             const ushort* __restrict__ wc1t,
                                             const float* __restrict__ bc1,
                                             ushort* __restrict__ h2) {
    __shared__ ushort As[2][64 * 32];
    __shared__ ushort Bs[2][128 * 32];
    int t = threadIdx.x, lane = t & 63, wid = t >> 6;
    int wr = wid >> 1, wc = wid & 1;
    int m0 = blockIdx.x * 64, n0 = blockIdx.y * 128;
    const ushort* asrc = hin + (size_t)m0 * 288;
    const ushort* bsrc = wc1t + (size_t)n0 * 288;

    int ar = t >> 2, ac = (t & 3) * 8;
    bf16x8 pa, pb[2];
    auto issue = [&](int kt) {
        pa = *reinterpret_cast<const bf16x8*>(asrc + (size_t)ar * 288 + kt + ac);
#pragma unroll
        for (int it = 0; it < 2; it++) {
            int e = (it * 256 + t) * 8;
            int rr = e >> 5, cc = e & 31;
            pb[it] = *reinterpret_cast<const bf16x8*>(bsrc + (size_t)rr * 288 + kt + cc);
        }
    };
    auto commit = [&](int buf) {
        char* ab = reinterpret_cast<char*>(&As[buf][0]);
        int off0 = (ar << 6) + ((ac << 1) ^ ((ar & 3) << 4));
        *reinterpret_cast<bf16x8*>(ab + off0) = pa;
        char* bb = reinterpret_cast<char*>(&Bs[buf][0]);
#pragma unroll
        for (int it = 0; it < 2; it++) {
            int e = (it * 256 + t) * 8;
            int rr = e >> 5, cc = e & 31;
            int off = (rr << 6) + ((cc << 1) ^ ((rr & 3) << 4));
            *reinterpret_cast<bf16x8*>(bb + off) = pb[it];
        }
    };

    f32x4 acc[2][4] = {};
    issue(0);
    commit(0);
    __syncthreads();
    int cur = 0;
    for (int kt = 0; kt < 288; kt += 32) {
        int nxt = kt + 32;
        if (nxt < 288) issue(nxt);
        int cb = ((lane >> 4) << 3) << 1;
        bf16x8 a[2], b[4];
#pragma unroll
        for (int i = 0; i < 2; i++) a[i] = frag32_ld(&As[cur][0], wr * 32 + i * 16 + (lane & 15), cb);
#pragma unroll
        for (int f = 0; f < 4; f++) b[f] = frag32_ld(&Bs[cur][0], wc * 64 + f * 16 + (lane & 15), cb);
#pragma unroll
        for (int i = 0; i < 2; i++)
#pragma unroll
            for (int j = 0; j < 4; j++)
                acc[i][j] = __builtin_amdgcn_mfma_f32_16x16x32_bf16(a[i], b[j], acc[i][j], 0, 0, 0);
        if (nxt < 288) commit(cur ^ 1);
        __syncthreads();
        cur ^= 1;
    }
    int rb = m0 + wr * 32 + ((lane >> 4) << 2);
    int cb0 = n0 + wc * 64 + (lane & 15);
#pragma unroll
    for (int j = 0; j < 4; j++) {
        int col = cb0 + j * 16;
        float bv = bc1[col];
#pragma unroll
        for (int i = 0; i < 2; i++)
#pragma unroll
            for (int q = 0; q < 4; q++) {
                int row = rb + i * 16 + q;
                float v = acc[i][j][q] + bv;
                v = v > 0.f ? v : 0.f;
                h2[(size_t)row * 256 + col] = f2bf(v);
            }
    }
}

// ---------------- final: out = h2 (3840x256 bf16) @ Wc2 (256x3 f32) + bc2
__global__ void final_fc(const ushort* __restrict__ h2,
                         const float* __restrict__ wc2,
                         const float* __restrict__ bc2,
                         float* __restrict__ out) {
    __shared__ float w[768];
    int t = threadIdx.x;
    for (int i = t; i < 768; i += 256) w[i] = wc2[i];
    __syncthreads();
    int g = t >> 4, l = t & 15;
    int row = blockIdx.x * 16 + g;
    const ushort* hr = h2 + (size_t)row * 256 + l * 16;
    bf16x8 v0 = *reinterpret_cast<const bf16x8*>(hr);
    bf16x8 v1 = *reinterpret_cast<const bf16x8*>(hr + 8);
    float s0 = 0.f, s1 = 0.f, s2 = 0.f;
#pragma unroll
    for (int k = 0; k < 8; k++) {
        float h = bf2f((ushort)v0[k]);
        int c = (l * 16 + k) * 3;
        s0 += h * w[c]; s1 += h * w[c + 1]; s2 += h * w[c + 2];
    }
#pragma unroll
    for (int k = 0; k < 8; k++) {
        float h = bf2f((ushort)v1[k]);
        int c = (l * 16 + 8 + k) * 3;
        s0 += h * w[c]; s1 += h * w[c + 1]; s2 += h * w[c + 2];
    }
#pragma unroll
    for (int m = 1; m < 16; m <<= 1) {
        s0 += __shfl_xor(s0, m);
        s1 += __shfl_xor(s1, m);
        s2 += __shfl_xor(s2, m);
    }
    if (l == 0) {
        out[row * 3 + 0] = s0 + bc2[0];
        out[row * 3 + 1] = s1 + bc2[1];
        out[row * 3 + 2] = s2 + bc2[2];
    }
}

extern "C" void kernel_launch(void* const* d_in, const int* in_sizes, int n_in,
                              void* d_out, int out_size, void* d_ws, size_t ws_size,
                              hipStream_t stream) {
    (void)in_sizes; (void)n_in; (void)out_size; (void)ws_size;
    const float* xs = (const float*)d_in[0];
    const float* xo = (const float*)d_in[1];
    const float* xu = (const float*)d_in[2];
    const float* boxes = (const float*)d_in[3];
    const float* im_info = (const float*)d_in[4];
    const int* o1 = (const int*)d_in[5];
    const int* o2 = (const int*)d_in[6];
    const int* uu = (const int*)d_in[7];
    const int* im = (const int*)d_in[8];
    const float* Ws1 = (const float*)d_in[9];
    const float* bs1 = (const float*)d_in[10];
    const float* Ws2 = (const float*)d_in[11];
    const float* bs2 = (const float*)d_in[12];
    const float* Wo1 = (const float*)d_in[13];
    const float* bo1 = (const float*)d_in[14];
    const float* Wo2 = (const float*)d_in[15];
    const float* bo2 = (const float*)d_in[16];
    const float* Wu1 = (const float*)d_in[17];
    const float* bu1 = (const float*)d_in[18];
    const float* Wu2 = (const float*)d_in[19];
    const float* bu2 = (const float*)d_in[20];
    const float* Wc1 = (const float*)d_in[21];
    const float* bc1 = (const float*)d_in[22];
    const float* Wc2 = (const float*)d_in[23];
    const float* bc2 = (const float*)d_in[24];
    float* out = (float*)d_out;

    ushort* W1T = (ushort*)d_ws;                      // 3 * 512*2048
    ushort* H2BR = W1T;                               // alias (used after gemm1 is done with W1T)
    ushort* W2T = W1T + (size_t)3 * 512 * 2048;       // 3 * 256*512
    ushort* WC1T = W2T + (size_t)3 * 256 * 512;       // 256*288
    ushort* H1 = WC1T + (size_t)256 * 288;            // 3 * 3840*512
    ushort* HIN = H1 + (size_t)3 * 3840 * 512;        // 3840*288
    ushort* H2 = HIN + (size_t)3840 * 288;            // 3840*256

    transpose_convert<<<dim3(32, 8, 3), 256, 0, stream>>>(Ws1, Wo1, Wu1, W1T, 2048, 512, 2048);
    transpose_convert2<<<dim3(8, 4, 4), 256, 0, stream>>>(Ws2, Wo2, Wu2, Wc1, W2T, WC1T);
    gemm1<<<1440, 64, 0, stream>>>(xs, xo, xu, W1T, bs1, bo1, bu1, H1);
    gemm2<<<360, 256, 0, stream>>>(H1, W2T, bs2, bo2, bu2, H2BR);
    appear_pack<<<480, 256, 0, stream>>>(H2BR, HIN, boxes, im_info, o1, o2, uu, im);
    gemm3<<<dim3(60, 2), 256, 0, stream>>>(HIN, WC1T, bc1, H2);
    final_fc<<<240, 256, 0, stream>>>(H2, Wc2, bc2, out);
}